// Round 1
// baseline (335.973 us; speedup 1.0000x reference)
//
#include <hip/hip_runtime.h>
#include <hip/hip_bf16.h>
#include <math.h>

typedef __bf16 bf16x8 __attribute__((ext_vector_type(8)));
typedef float f32x4 __attribute__((ext_vector_type(4)));

#define B_SZ 32
#define T_SZ 2048
#define D_SZ 512
#define K_SZ 128
#define TC 32
#define NC 64   // T_SZ / TC

__device__ __forceinline__ float softplus_f(float x){
  return x > 20.f ? x : log1pf(expf(x));
}

// ---------------------------------------------------------------------------
// Kernel 1: spectral norm power iteration + W_sn -> bf16 (pre-scaled by 1/sigma)
// ---------------------------------------------------------------------------
__global__ __launch_bounds__(512) void sn_prep(const float* __restrict__ W,
                                               const float* __restrict__ u_sn,
                                               __bf16* __restrict__ Wb){
  __shared__ float red[512];
  __shared__ float vsh[512];
  __shared__ float ush[128];
  const int t = threadIdx.x;
  if (t < 128) ush[t] = u_sn[t];
  __syncthreads();
  // t1[d] = sum_k W[k,d] * u[k]   (coalesced over d)
  float t1 = 0.f;
  for (int k = 0; k < K_SZ; ++k) t1 += W[k*D_SZ + t] * ush[k];
  red[t] = t1 * t1;
  __syncthreads();
  for (int s = 256; s > 0; s >>= 1){ if (t < s) red[t] += red[t+s]; __syncthreads(); }
  const float n1 = sqrtf(red[0]);
  vsh[t] = t1 / (n1 + 1e-6f);
  __syncthreads();
  // t2[k] = sum_d W[k,d] * v[d]
  float t2 = 0.f;
  if (t < 128){
    const float* Wr = W + (size_t)t * D_SZ;
    for (int d = 0; d < D_SZ; ++d) t2 += Wr[d] * vsh[d];
  }
  __syncthreads();
  red[t] = (t < 128) ? t2*t2 : 0.f;
  __syncthreads();
  for (int s = 256; s > 0; s >>= 1){ if (t < s) red[t] += red[t+s]; __syncthreads(); }
  const float n2sq = red[0];
  const float sigma = n2sq / (sqrtf(n2sq) + 1e-6f);   // u1 . (W v)
  const float inv = 1.f / sigma;
  for (int i = t; i < K_SZ*D_SZ; i += 512) Wb[i] = (__bf16)(W[i] * inv);
}

// ---------------------------------------------------------------------------
// Kernel 2: u = x @ W_sn^T   (M=65536, N=128, K=512), bf16 MFMA, fp32 out
// LDS in fragment order: chunk c = fragblock*64 + lane, each chunk = 8 bf16.
// ---------------------------------------------------------------------------
__global__ __launch_bounds__(256) void gemm_xw(const float* __restrict__ X,
                                               const __bf16* __restrict__ Wb,
                                               float* __restrict__ U){
  __shared__ bf16x8 As[1024];   // 128(M) x 64(K) bf16 = 16 KB
  __shared__ bf16x8 Bs[1024];   // 128(N) x 64(K) bf16 = 16 KB
  const int tid = threadIdx.x;
  const int lane = tid & 63;
  const int wid = tid >> 6;
  const int wm = wid >> 1, wn = wid & 1;
  const int rowbase = blockIdx.x * 128;
  const int L15 = lane & 15, Lq = lane >> 4;
  f32x4 acc[4][4] = {};

  for (int kk = 0; kk < D_SZ; kk += 64){
    #pragma unroll
    for (int r = 0; r < 4; ++r){
      const int c = tid + 256*r;          // 0..1023
      const int L = c & 63, fb = c >> 6;  // 16 fragment blocks
      const int i = fb >> 1, s = fb & 1;
      const int row = i*16 + (L & 15);
      const int gcol = kk + s*32 + ((L >> 4) << 3);
      // A: fp32 -> bf16
      const float4* p = (const float4*)(X + (size_t)(rowbase + row)*D_SZ + gcol);
      const float4 v0 = p[0], v1 = p[1];
      bf16x8 f;
      f[0]=(__bf16)v0.x; f[1]=(__bf16)v0.y; f[2]=(__bf16)v0.z; f[3]=(__bf16)v0.w;
      f[4]=(__bf16)v1.x; f[5]=(__bf16)v1.y; f[6]=(__bf16)v1.z; f[7]=(__bf16)v1.w;
      As[c] = f;
      // B: already bf16 (L2-resident, 128 KB total)
      Bs[c] = *(const bf16x8*)(Wb + (size_t)row*D_SZ + gcol);
    }
    __syncthreads();
    #pragma unroll
    for (int s = 0; s < 2; ++s){
      bf16x8 af[4], bfr[4];
      #pragma unroll
      for (int ii = 0; ii < 4; ++ii) af[ii]  = As[((wm*4+ii)*2 + s)*64 + lane];
      #pragma unroll
      for (int jj = 0; jj < 4; ++jj) bfr[jj] = Bs[((wn*4+jj)*2 + s)*64 + lane];
      #pragma unroll
      for (int ii = 0; ii < 4; ++ii)
        #pragma unroll
        for (int jj = 0; jj < 4; ++jj)
          acc[ii][jj] = __builtin_amdgcn_mfma_f32_16x16x32_bf16(af[ii], bfr[jj], acc[ii][jj], 0, 0, 0);
    }
    __syncthreads();
  }
  // epilogue: C/D layout col = lane&15, row = (lane>>4)*4 + reg (m89-verified)
  #pragma unroll
  for (int ii = 0; ii < 4; ++ii){
    const int m = rowbase + (wm*4+ii)*16 + (Lq << 2);
    #pragma unroll
    for (int jj = 0; jj < 4; ++jj){
      const int n = (wn*4+jj)*16 + L15;
      #pragma unroll
      for (int r = 0; r < 4; ++r)
        U[(size_t)(m + r)*K_SZ + n] = acc[ii][jj][r];
    }
  }
}

// ---------------------------------------------------------------------------
// Kernel 3 (pass A): per-chunk summaries: sum(alpha*dt), sum(theta), local z
// block = (chunk c, batch b), 128 threads = one per k
// ---------------------------------------------------------------------------
__global__ __launch_bounds__(128) void pass_a(
    const float* __restrict__ alpha_mod, const float* __restrict__ omega_mod,
    const float* __restrict__ Uarr, const float* __restrict__ dt,
    const float* __restrict__ tau_mod, const float* __restrict__ s_real,
    const float* __restrict__ s_imag, const float* __restrict__ tau_raw,
    const float* __restrict__ bvec,
    float* __restrict__ sumA, float* __restrict__ sumT,
    float* __restrict__ Zr, float* __restrict__ Zi){
  const int k = threadIdx.x;
  const int c = blockIdx.x, b = blockIdx.y;
  const float tau = softplus_f(tau_raw[0]) + 1e-3f;
  const float a0 = (softplus_f(s_real[k]) + 1e-6f) * tau;
  const float w0 = s_imag[k] * tau;
  const float bk = bvec[k];
  __shared__ float sdt[TC], ssc[TC];
  const int t0 = c * TC;
  if (k < TC) sdt[k] = dt[b*T_SZ + t0 + k];
  else if (k < 2*TC) ssc[k-TC] = __expf(tau_mod[b*T_SZ + t0 + k - TC]);
  __syncthreads();
  float zr = 0.f, zs = 0.f, sA = 0.f, sT = 0.f;
  const size_t base = ((size_t)(b*T_SZ + t0))*K_SZ + k;
  #pragma unroll 4
  for (int i = 0; i < TC; ++i){
    const float am = alpha_mod[base + (size_t)i*K_SZ];
    const float om = omega_mod[base + (size_t)i*K_SZ];
    const float uu = Uarr[base + (size_t)i*K_SZ] + bk;
    const float scdt = ssc[i] * sdt[i];
    const float ad = a0 * __expf(am) * scdt;
    const float th = w0 * __expf(om) * scdt;
    const float rho = __expf(-ad);
    float st, ct; __sincosf(th, &st, &ct);
    const float nr = rho*(zr*ct - zs*st) + uu;
    const float ns = rho*(zr*st + zs*ct);
    zr = nr; zs = ns;
    sA += ad; sT += th;
  }
  const size_t idx = ((size_t)(b*NC + c))*K_SZ + k;
  sumA[idx] = sA; sumT[idx] = sT; Zr[idx] = zr; Zi[idx] = zs;
}

// ---------------------------------------------------------------------------
// Kernel 4 (pass B): sequential scan of chunk summaries -> carry-in per chunk
// ---------------------------------------------------------------------------
__global__ __launch_bounds__(256) void pass_b(
    const float* __restrict__ sumA, const float* __restrict__ sumT,
    const float* __restrict__ Zr, const float* __restrict__ Zi,
    float* __restrict__ Cr, float* __restrict__ Ci){
  const int id = blockIdx.x*256 + threadIdx.x;  // 0..4095 = b*128 + k
  const int b = id >> 7, k = id & 127;
  float er = 0.f, ei = 0.f;
  #pragma unroll 8
  for (int c = 0; c < NC; ++c){
    const size_t idx = ((size_t)(b*NC + c))*K_SZ + k;
    Cr[idx] = er; Ci[idx] = ei;                 // state entering chunk c
    const float rho = __expf(-sumA[idx]);
    float st, ct; __sincosf(sumT[idx], &st, &ct);
    const float ar = rho*ct, ai = rho*st;
    const float nr = Zr[idx] + ar*er - ai*ei;   // E_c = Z_c + A_c * E_{c-1}
    const float ni = Zi[idx] + ar*ei + ai*er;
    er = nr; ei = ni;
  }
}

// ---------------------------------------------------------------------------
// Kernel 5 (pass C): replay chunks from carry-in, write [B,T,2K] output
// ---------------------------------------------------------------------------
__global__ __launch_bounds__(128) void pass_c(
    const float* __restrict__ alpha_mod, const float* __restrict__ omega_mod,
    const float* __restrict__ Uarr, const float* __restrict__ dt,
    const float* __restrict__ tau_mod, const float* __restrict__ s_real,
    const float* __restrict__ s_imag, const float* __restrict__ tau_raw,
    const float* __restrict__ bvec,
    const float* __restrict__ Cr, const float* __restrict__ Ci,
    float* __restrict__ out){
  const int k = threadIdx.x;
  const int c = blockIdx.x, b = blockIdx.y;
  const float tau = softplus_f(tau_raw[0]) + 1e-3f;
  const float a0 = (softplus_f(s_real[k]) + 1e-6f) * tau;
  const float w0 = s_imag[k] * tau;
  const float bk = bvec[k];
  __shared__ float sdt[TC], ssc[TC];
  const int t0 = c * TC;
  if (k < TC) sdt[k] = dt[b*T_SZ + t0 + k];
  else if (k < 2*TC) ssc[k-TC] = __expf(tau_mod[b*T_SZ + t0 + k - TC]);
  __syncthreads();
  const size_t cidx = ((size_t)(b*NC + c))*K_SZ + k;
  float zr = Cr[cidx], zs = Ci[cidx];
  const size_t base = ((size_t)(b*T_SZ + t0))*K_SZ + k;
  const size_t obase = ((size_t)(b*T_SZ + t0))*(2*K_SZ) + k;
  #pragma unroll 4
  for (int i = 0; i < TC; ++i){
    const float am = alpha_mod[base + (size_t)i*K_SZ];
    const float om = omega_mod[base + (size_t)i*K_SZ];
    const float uu = Uarr[base + (size_t)i*K_SZ] + bk;
    const float scdt = ssc[i] * sdt[i];
    const float ad = a0 * __expf(am) * scdt;
    const float th = w0 * __expf(om) * scdt;
    const float rho = __expf(-ad);
    float st, ct; __sincosf(th, &st, &ct);
    const float nr = rho*(zr*ct - zs*st) + uu;
    const float ns = rho*(zr*st + zs*ct);
    zr = nr; zs = ns;
    out[obase + (size_t)i*(2*K_SZ)] = zr;
    out[obase + (size_t)i*(2*K_SZ) + K_SZ] = zs;
  }
}

// ---------------------------------------------------------------------------
extern "C" void kernel_launch(void* const* d_in, const int* in_sizes, int n_in,
                              void* d_out, int out_size, void* d_ws, size_t ws_size,
                              hipStream_t stream){
  (void)in_sizes; (void)n_in; (void)out_size; (void)ws_size;
  const float* x         = (const float*)d_in[0];
  const float* dt        = (const float*)d_in[1];
  const float* alpha_mod = (const float*)d_in[2];
  const float* omega_mod = (const float*)d_in[3];
  const float* tau_mod   = (const float*)d_in[4];
  const float* s_real    = (const float*)d_in[5];
  const float* s_imag    = (const float*)d_in[6];
  const float* tau_raw   = (const float*)d_in[7];
  const float* W         = (const float*)d_in[8];
  const float* bvec      = (const float*)d_in[9];
  const float* u_sn      = (const float*)d_in[10];
  float* out = (float*)d_out;

  char* w = (char*)d_ws;
  __bf16* Wb = (__bf16*)w;                                  // 128 KiB
  float* U   = (float*)(w + 131072);                        // 32 MiB (u = x@W^T)
  size_t off = 131072 + (size_t)B_SZ*T_SZ*K_SZ*4;
  const size_t SUMN = (size_t)B_SZ*NC*K_SZ*4;               // 1 MiB each
  float* sumA = (float*)(w + off); off += SUMN;
  float* sumT = (float*)(w + off); off += SUMN;
  float* Zr   = (float*)(w + off); off += SUMN;
  float* Zi   = (float*)(w + off); off += SUMN;
  float* Cr   = (float*)(w + off); off += SUMN;
  float* Ci   = (float*)(w + off); off += SUMN;

  sn_prep<<<1, 512, 0, stream>>>(W, u_sn, Wb);
  gemm_xw<<<(B_SZ*T_SZ)/128, 256, 0, stream>>>(x, Wb, U);
  pass_a<<<dim3(NC, B_SZ), 128, 0, stream>>>(alpha_mod, omega_mod, U, dt, tau_mod,
                                             s_real, s_imag, tau_raw, bvec,
                                             sumA, sumT, Zr, Zi);
  pass_b<<<16, 256, 0, stream>>>(sumA, sumT, Zr, Zi, Cr, Ci);
  pass_c<<<dim3(NC, B_SZ), 128, 0, stream>>>(alpha_mod, omega_mod, U, dt, tau_mod,
                                             s_real, s_imag, tau_raw, bvec,
                                             Cr, Ci, out);
}